// Round 1
// baseline (2511.995 us; speedup 1.0000x reference)
//
#include <hip/hip_runtime.h>

#define NFEAT 128

// Y[row] = act(W * X[row] + b), W is [128,128] row-major ([out,in]).
// One block of 128 threads per row; thread t computes output feature t.
__global__ __launch_bounds__(128) void gemm_bias_act(
    const float* __restrict__ X, const float* __restrict__ W,
    const float* __restrict__ b, float* __restrict__ Y,
    int n, int relu)
{
    __shared__ float xs[NFEAT];
    const int row = blockIdx.x;
    const int t = threadIdx.x;
    if (row >= n) return;

    xs[t] = X[(size_t)row * NFEAT + t];
    __syncthreads();

    const float4* w4 = reinterpret_cast<const float4*>(W + (size_t)t * NFEAT);
    float acc = 0.f;
#pragma unroll
    for (int k = 0; k < NFEAT / 4; ++k) {
        const float4 wv = w4[k];
        acc = fmaf(xs[4 * k + 0], wv.x, acc);
        acc = fmaf(xs[4 * k + 1], wv.y, acc);
        acc = fmaf(xs[4 * k + 2], wv.z, acc);
        acc = fmaf(xs[4 * k + 3], wv.w, acc);
    }
    acc += b[t];
    if (relu) acc = fmaxf(acc, 0.f);
    Y[(size_t)row * NFEAT + t] = acc;
}

// agg[dst[e]] += h[src[e]] for all edges; one thread per (edge, 4-feature group).
__global__ __launch_bounds__(256) void scatter_edges(
    const float* __restrict__ h, const int* __restrict__ src,
    const int* __restrict__ dst, float* __restrict__ agg, int nE)
{
    const long total = (long)nE * (NFEAT / 4);
    const long stride = (long)gridDim.x * blockDim.x;
    for (long i = (long)blockIdx.x * blockDim.x + threadIdx.x; i < total; i += stride) {
        const int e = (int)(i >> 5);        // NFEAT/4 == 32
        const int g = (int)(i & 31);
        const int s = src[e];
        const int d = dst[e];
        const float4 v = *reinterpret_cast<const float4*>(h + (size_t)s * NFEAT + g * 4);
        float* o = agg + (size_t)d * NFEAT + g * 4;
        atomicAdd(o + 0, v.x);
        atomicAdd(o + 1, v.y);
        atomicAdd(o + 2, v.z);
        atomicAdd(o + 3, v.w);
    }
}

extern "C" void kernel_launch(void* const* d_in, const int* in_sizes, int n_in,
                              void* d_out, int out_size, void* d_ws, size_t ws_size,
                              hipStream_t stream) {
    const float* node_feats = (const float*)d_in[0];
    const int*   src        = (const int*)d_in[1];
    const int*   dst        = (const int*)d_in[2];
    const float* W_msg      = (const float*)d_in[3];
    const float* b_msg      = (const float*)d_in[4];
    const float* W_out      = (const float*)d_in[5];
    const float* b_out      = (const float*)d_in[6];

    const int nNodes = in_sizes[0] / NFEAT;
    const int nEdges = in_sizes[1];

    float* out = (float*)d_out;
    float* h   = out;             // reuse d_out as scratch for per-node messages
    float* agg = (float*)d_ws;    // [nNodes * NFEAT] aggregation buffer

    // Zero the aggregation buffer (graph-capture-safe memset).
    hipMemsetAsync(agg, 0, (size_t)nNodes * NFEAT * sizeof(float), stream);

    // Phase 1: h = relu(node_feats @ W_msg^T + b_msg)
    gemm_bias_act<<<nNodes, NFEAT, 0, stream>>>(node_feats, W_msg, b_msg, h, nNodes, 1);

    // Phase 2: agg[dst] += h[src]
    scatter_edges<<<4096, 256, 0, stream>>>(h, src, dst, agg, nEdges);

    // Phase 3: out = agg @ W_out^T + b_out
    gemm_bias_act<<<nNodes, NFEAT, 0, stream>>>(agg, W_out, b_out, out, nNodes, 0);
}

// Round 2
// 552.600 us; speedup vs baseline: 4.5458x; 4.5458x over previous
//
#include <hip/hip_runtime.h>

#define NFEAT 128

// ---------------------------------------------------------------------------
// Tiled f32 GEMM: Y[row] = act(W * X[row] + b). W is [128,128] row-major
// ([out,in]). Block = 256 threads computes 64 rows x 128 cols.
// X tile staged in LDS (32KB -> 2 blocks/CU); W streamed via L1/L2 (float4,
// k-ordered 2KB working set stays hot). Per-thread 4x8 register tile.
// ---------------------------------------------------------------------------
__global__ __launch_bounds__(256) void gemm128(
    const float* __restrict__ X, const float* __restrict__ W,
    const float* __restrict__ bias, float* __restrict__ Y,
    int n, int relu)
{
    __shared__ float xs[64][NFEAT];
    const int t = threadIdx.x;
    const int row0 = blockIdx.x * 64;

    // Stage X tile (64 rows x 128) as float4, guard OOB rows.
    for (int j = t; j < 64 * 32; j += 256) {
        const int r = j >> 5, cg = j & 31;
        const int row = row0 + r;
        float4 x = (row < n)
            ? reinterpret_cast<const float4*>(X + (size_t)row * NFEAT)[cg]
            : make_float4(0.f, 0.f, 0.f, 0.f);
        *reinterpret_cast<float4*>(&xs[r][cg * 4]) = x;
    }
    __syncthreads();

    const int tx = t & 15;   // col group: cols tx + 16*c
    const int ty = t >> 4;   // row group: rows ty*4 + r
    float acc[4][8];
#pragma unroll
    for (int r = 0; r < 4; ++r)
#pragma unroll
        for (int c = 0; c < 8; ++c) acc[r][c] = 0.f;

    for (int k = 0; k < NFEAT; k += 4) {
        float4 xa[4], wb[8];
#pragma unroll
        for (int r = 0; r < 4; ++r)
            xa[r] = *reinterpret_cast<const float4*>(&xs[ty * 4 + r][k]);
#pragma unroll
        for (int c = 0; c < 8; ++c)
            wb[c] = *reinterpret_cast<const float4*>(W + (size_t)(tx + 16 * c) * NFEAT + k);
#pragma unroll
        for (int r = 0; r < 4; ++r)
#pragma unroll
            for (int c = 0; c < 8; ++c) {
                acc[r][c] = fmaf(xa[r].x, wb[c].x, acc[r][c]);
                acc[r][c] = fmaf(xa[r].y, wb[c].y, acc[r][c]);
                acc[r][c] = fmaf(xa[r].z, wb[c].z, acc[r][c]);
                acc[r][c] = fmaf(xa[r].w, wb[c].w, acc[r][c]);
            }
    }

#pragma unroll
    for (int r = 0; r < 4; ++r) {
        const int row = row0 + ty * 4 + r;
        if (row >= n) continue;
#pragma unroll
        for (int c = 0; c < 8; ++c) {
            const int col = tx + 16 * c;
            float v = acc[r][c];
            if (bias) v += bias[col];
            if (relu) v = fmaxf(v, 0.f);
            Y[(size_t)row * NFEAT + col] = v;
        }
    }
}

// ---------------------------------------------------------------------------
// CSR-by-dst construction
// ---------------------------------------------------------------------------
__global__ __launch_bounds__(256) void count_edges(
    const int* __restrict__ dst, int* __restrict__ counts, int nE)
{
    const int i = blockIdx.x * 256 + threadIdx.x;
    if (i < nE) atomicAdd(&counts[dst[i]], 1);
}

// Block-level exclusive scan (Hillis-Steele), writes per-block exclusive
// results to `offsets` and block totals to `blocksums`.
__global__ __launch_bounds__(256) void scan_block(
    const int* __restrict__ counts, int* __restrict__ offsets,
    int* __restrict__ blocksums, int n)
{
    __shared__ int s[256];
    const int t = threadIdx.x;
    const int i = blockIdx.x * 256 + t;
    const int v = (i < n) ? counts[i] : 0;
    s[t] = v;
    __syncthreads();
    for (int off = 1; off < 256; off <<= 1) {
        const int add = (t >= off) ? s[t - off] : 0;
        __syncthreads();
        s[t] += add;
        __syncthreads();
    }
    if (i < n) offsets[i] = s[t] - v;  // exclusive within block
    if (t == 255) blocksums[blockIdx.x] = s[255];
}

// Single-block exclusive scan of the block sums (nb <= 512).
__global__ __launch_bounds__(512) void scan_sums(int* __restrict__ blocksums, int nb)
{
    __shared__ int s[512];
    const int t = threadIdx.x;
    const int v = (t < nb) ? blocksums[t] : 0;
    s[t] = v;
    __syncthreads();
    for (int off = 1; off < 512; off <<= 1) {
        const int add = (t >= off) ? s[t - off] : 0;
        __syncthreads();
        s[t] += add;
        __syncthreads();
    }
    if (t < nb) blocksums[t] = s[t] - v;  // exclusive
}

__global__ __launch_bounds__(256) void add_offsets(
    int* __restrict__ offsets, int* __restrict__ cursor,
    const int* __restrict__ blocksums, int n)
{
    const int i = blockIdx.x * 256 + threadIdx.x;
    if (i < n) {
        const int o = offsets[i] + blocksums[blockIdx.x];
        offsets[i] = o;
        cursor[i] = o;
    }
}

__global__ __launch_bounds__(256) void fill_edges(
    const int* __restrict__ src, const int* __restrict__ dst,
    int* __restrict__ cursor, int* __restrict__ esrc, int nE)
{
    const int i = blockIdx.x * 256 + threadIdx.x;
    if (i < nE) {
        const int p = atomicAdd(&cursor[dst[i]], 1);
        esrc[p] = src[i];
    }
}

// ---------------------------------------------------------------------------
// out[d] = b_out + sum_{e: dst=d} g[src[e]]  (atomic-free gather-sum).
// 8 nodes per 256-thread block; 32 lanes x float4 per node row.
// After fill_edges, cursor[d] == offsets[d] + deg[d] (= row end).
// ---------------------------------------------------------------------------
__global__ __launch_bounds__(256) void gather_sum(
    const float* __restrict__ g, const int* __restrict__ offsets,
    const int* __restrict__ cursor, const int* __restrict__ esrc,
    const float* __restrict__ bias, float* __restrict__ out, int nNodes)
{
    const int node = blockIdx.x * 8 + (threadIdx.x >> 5);
    const int t4 = threadIdx.x & 31;
    if (node >= nNodes) return;
    float4 acc = reinterpret_cast<const float4*>(bias)[t4];
    const int beg = offsets[node];
    const int end = cursor[node];
    for (int i = beg; i < end; ++i) {
        const int s = esrc[i];
        const float4 v = reinterpret_cast<const float4*>(g + (size_t)s * NFEAT)[t4];
        acc.x += v.x; acc.y += v.y; acc.z += v.z; acc.w += v.w;
    }
    reinterpret_cast<float4*>(out + (size_t)node * NFEAT)[t4] = acc;
}

extern "C" void kernel_launch(void* const* d_in, const int* in_sizes, int n_in,
                              void* d_out, int out_size, void* d_ws, size_t ws_size,
                              hipStream_t stream) {
    const float* node_feats = (const float*)d_in[0];
    const int*   src        = (const int*)d_in[1];
    const int*   dst        = (const int*)d_in[2];
    const float* W_msg      = (const float*)d_in[3];
    const float* b_msg      = (const float*)d_in[4];
    const float* W_out      = (const float*)d_in[5];
    const float* b_out      = (const float*)d_in[6];

    const int nNodes = in_sizes[0] / NFEAT;
    const int nEdges = in_sizes[1];

    float* out = (float*)d_out;
    float* h   = out;  // phase-1 output lives in d_out (overwritten by gather at the end)

    // Workspace layout (~55 MB): g | counts | offsets | cursor | blocksums | esrc
    float* g         = (float*)d_ws;                       // nNodes*128 f32
    int*   counts    = (int*)(g + (size_t)nNodes * NFEAT); // nNodes
    int*   offsets   = counts + nNodes;                    // nNodes
    int*   cursor    = offsets + nNodes;                   // nNodes
    int*   blocksums = cursor + nNodes;                    // 512
    int*   esrc      = blocksums + 512;                    // nEdges

    const int nb1 = (nNodes + 255) / 256;   // 391 (must be <= 512 for scan_sums)
    const int nbe = (nEdges + 255) / 256;   // 2500

    // --- CSR build (only depends on dst) ---
    hipMemsetAsync(counts, 0, (size_t)nNodes * sizeof(int), stream);
    count_edges<<<nbe, 256, 0, stream>>>(dst, counts, nEdges);
    scan_block<<<nb1, 256, 0, stream>>>(counts, offsets, blocksums, nNodes);
    scan_sums<<<1, 512, 0, stream>>>(blocksums, nb1);
    add_offsets<<<nb1, 256, 0, stream>>>(offsets, cursor, blocksums, nNodes);
    fill_edges<<<nbe, 256, 0, stream>>>(src, dst, cursor, esrc, nEdges);

    // --- h = relu(X @ Wm^T + bm) ; g = h @ Wo^T (bias folded into gather) ---
    const int ngb = (nNodes + 63) / 64;     // 1563
    gemm128<<<ngb, 256, 0, stream>>>(node_feats, W_msg, b_msg, h, nNodes, 1);
    gemm128<<<ngb, 256, 0, stream>>>(h, W_out, nullptr, g, nNodes, 0);

    // --- out[d] = b_out + sum g[src[e]] over incoming edges ---
    gather_sum<<<(nNodes + 7) / 8, 256, 0, stream>>>(g, offsets, cursor, esrc, b_out, out, nNodes);
}

// Round 3
// 200.867 us; speedup vs baseline: 12.5058x; 2.7511x over previous
//
#include <hip/hip_runtime.h>
#include <hip/hip_bf16.h>

#define NFEAT 128

typedef short bf16x8 __attribute__((ext_vector_type(8)));   // 8 bf16 as i16
typedef float f32x4  __attribute__((ext_vector_type(4)));

static __device__ __forceinline__ short f2bf(float f) {
    __hip_bfloat16 h = __float2bfloat16(f);   // round-to-nearest
    return __builtin_bit_cast(short, h);
}
static __device__ __forceinline__ float bf2f(unsigned short u) {
    unsigned int x = ((unsigned int)u) << 16;
    return __builtin_bit_cast(float, x);
}

// ---------------------------------------------------------------------------
// Convert both weight matrices (128x128 f32 each) to bf16.
// ---------------------------------------------------------------------------
__global__ __launch_bounds__(256) void convert_w(
    const float* __restrict__ wa, const float* __restrict__ wb,
    short* __restrict__ oa, short* __restrict__ ob)
{
    const int i = blockIdx.x * 256 + threadIdx.x;
    if (i < NFEAT * NFEAT) { oa[i] = f2bf(wa[i]); ob[i] = f2bf(wb[i]); }
}

// ---------------------------------------------------------------------------
// MFMA GEMM: Y[row,col] = act(sum_k X[row,k]*W[col,k] + bias[col]), bf16 out.
// Block = 256 thr = 4 waves; wave w owns rows row0+w*16..+15, all 128 cols.
// No LDS. A-frag from global (f32->bf16 if IN_F32), B-frag from bf16 W
// (32 KB, L1-resident). n % 16 == 0 so whole-wave OOB guard suffices.
// ---------------------------------------------------------------------------
template<int IN_F32, int RELU>
__global__ __launch_bounds__(256) void gemm_mfma(
    const void* __restrict__ Xv, const short* __restrict__ Wb,
    const float* __restrict__ bias, short* __restrict__ Y, int n)
{
    const int w  = threadIdx.x >> 6;
    const int l  = threadIdx.x & 63;
    const int row0 = blockIdx.x * 64 + w * 16;
    if (row0 >= n) return;
    const int lr = l & 15;     // A row / B col / D col (within subtile)
    const int lk = l >> 4;     // k-group 0..3
    const int row = row0 + lr;

    f32x4 acc[8];
#pragma unroll
    for (int c = 0; c < 8; ++c) acc[c] = (f32x4){0.f, 0.f, 0.f, 0.f};

#pragma unroll
    for (int k0 = 0; k0 < NFEAT; k0 += 32) {
        const int ka = k0 + lk * 8;
        bf16x8 a;
        if (IN_F32) {
            const float* xp = (const float*)Xv + (size_t)row * NFEAT + ka;
            const float4 x0 = *(const float4*)xp;
            const float4 x1 = *(const float4*)(xp + 4);
            a[0] = f2bf(x0.x); a[1] = f2bf(x0.y); a[2] = f2bf(x0.z); a[3] = f2bf(x0.w);
            a[4] = f2bf(x1.x); a[5] = f2bf(x1.y); a[6] = f2bf(x1.z); a[7] = f2bf(x1.w);
        } else {
            a = *(const bf16x8*)((const short*)Xv + (size_t)row * NFEAT + ka);
        }
#pragma unroll
        for (int c = 0; c < 8; ++c) {
            const bf16x8 b = *(const bf16x8*)(Wb + (size_t)(c * 16 + lr) * NFEAT + ka);
            acc[c] = __builtin_amdgcn_mfma_f32_16x16x32_bf16(a, b, acc[c], 0, 0, 0);
        }
    }

#pragma unroll
    for (int c = 0; c < 8; ++c) {
        const int col = c * 16 + lr;
        const float bv = bias ? bias[col] : 0.f;
#pragma unroll
        for (int r = 0; r < 4; ++r) {
            const int orow = row0 + lk * 4 + r;
            float v = acc[c][r] + bv;
            if (RELU) v = fmaxf(v, 0.f);
            Y[(size_t)orow * NFEAT + col] = f2bf(v);
        }
    }
}

// ---------------------------------------------------------------------------
// CSR-by-dst construction (validated in round 2).
// ---------------------------------------------------------------------------
__global__ __launch_bounds__(256) void count_edges(
    const int* __restrict__ dst, int* __restrict__ counts, int nE)
{
    const int i = blockIdx.x * 256 + threadIdx.x;
    if (i < nE) atomicAdd(&counts[dst[i]], 1);
}

__global__ __launch_bounds__(256) void scan_block(
    const int* __restrict__ counts, int* __restrict__ offsets,
    int* __restrict__ blocksums, int n)
{
    __shared__ int s[256];
    const int t = threadIdx.x;
    const int i = blockIdx.x * 256 + t;
    const int v = (i < n) ? counts[i] : 0;
    s[t] = v;
    __syncthreads();
    for (int off = 1; off < 256; off <<= 1) {
        const int add = (t >= off) ? s[t - off] : 0;
        __syncthreads();
        s[t] += add;
        __syncthreads();
    }
    if (i < n) offsets[i] = s[t] - v;
    if (t == 255) blocksums[blockIdx.x] = s[255];
}

__global__ __launch_bounds__(512) void scan_sums(int* __restrict__ blocksums, int nb)
{
    __shared__ int s[512];
    const int t = threadIdx.x;
    const int v = (t < nb) ? blocksums[t] : 0;
    s[t] = v;
    __syncthreads();
    for (int off = 1; off < 512; off <<= 1) {
        const int add = (t >= off) ? s[t - off] : 0;
        __syncthreads();
        s[t] += add;
        __syncthreads();
    }
    if (t < nb) blocksums[t] = s[t] - v;
}

__global__ __launch_bounds__(256) void add_offsets(
    int* __restrict__ offsets, int* __restrict__ cursor,
    const int* __restrict__ blocksums, int n)
{
    const int i = blockIdx.x * 256 + threadIdx.x;
    if (i < n) {
        const int o = offsets[i] + blocksums[blockIdx.x];
        offsets[i] = o;
        cursor[i] = o;
    }
}

__global__ __launch_bounds__(256) void fill_edges(
    const int* __restrict__ src, const int* __restrict__ dst,
    int* __restrict__ cursor, int* __restrict__ esrc, int nE)
{
    const int i = blockIdx.x * 256 + threadIdx.x;
    if (i < nE) {
        const int p = atomicAdd(&cursor[dst[i]], 1);
        esrc[p] = src[i];
    }
}

// ---------------------------------------------------------------------------
// out[d] = b_out + sum_{e: dst=d} g[src[e]]   (g is bf16, out is f32).
// 8 nodes per 256-thread block; 32 lanes x 4 feats per node.
// ---------------------------------------------------------------------------
__global__ __launch_bounds__(256) void gather_sum(
    const unsigned short* __restrict__ g, const int* __restrict__ offsets,
    const int* __restrict__ cursor, const int* __restrict__ esrc,
    const float* __restrict__ bias, float* __restrict__ out, int nNodes)
{
    const int node = blockIdx.x * 8 + (threadIdx.x >> 5);
    const int t4 = threadIdx.x & 31;
    if (node >= nNodes) return;
    float4 acc = *(const float4*)(bias + t4 * 4);
    const int beg = offsets[node];
    const int end = cursor[node];
    for (int i = beg; i < end; ++i) {
        const int s = esrc[i];
        const ushort4 v = *(const ushort4*)(g + (size_t)s * NFEAT + t4 * 4);
        acc.x += bf2f(v.x); acc.y += bf2f(v.y);
        acc.z += bf2f(v.z); acc.w += bf2f(v.w);
    }
    *(float4*)(out + (size_t)node * NFEAT + t4 * 4) = acc;
}

extern "C" void kernel_launch(void* const* d_in, const int* in_sizes, int n_in,
                              void* d_out, int out_size, void* d_ws, size_t ws_size,
                              hipStream_t stream) {
    const float* node_feats = (const float*)d_in[0];
    const int*   src        = (const int*)d_in[1];
    const int*   dst        = (const int*)d_in[2];
    const float* W_msg      = (const float*)d_in[3];
    const float* b_msg      = (const float*)d_in[4];
    const float* W_out      = (const float*)d_in[5];
    const float* b_out      = (const float*)d_in[6];

    const int nNodes = in_sizes[0] / NFEAT;
    const int nEdges = in_sizes[1];

    float* out = (float*)d_out;

    // ws layout: hbf | gbf | wm_bf | wo_bf | counts | offsets | cursor | blocksums | esrc
    short* hbf      = (short*)d_ws;                                  // nNodes*128 bf16
    short* gbf      = hbf + (size_t)nNodes * NFEAT;                  // nNodes*128 bf16
    short* wm_bf    = gbf + (size_t)nNodes * NFEAT;                  // 16384 bf16
    short* wo_bf    = wm_bf + NFEAT * NFEAT;                         // 16384 bf16
    int*   counts   = (int*)(wo_bf + NFEAT * NFEAT);                 // nNodes
    int*   offsets  = counts + nNodes;                               // nNodes
    int*   cursor   = offsets + nNodes;                              // nNodes
    int*   blocksums= cursor + nNodes;                               // 512
    int*   esrc     = blocksums + 512;                               // nEdges

    const int nb1 = (nNodes + 255) / 256;   // 391 (<= 512)
    const int nbe = (nEdges + 255) / 256;   // 2500
    const int ngb = (nNodes + 63) / 64;     // 1563

    // --- weight conversion + CSR build ---
    convert_w<<<(NFEAT * NFEAT + 255) / 256, 256, 0, stream>>>(W_msg, W_out, wm_bf, wo_bf);
    hipMemsetAsync(counts, 0, (size_t)nNodes * sizeof(int), stream);
    count_edges<<<nbe, 256, 0, stream>>>(dst, counts, nEdges);
    scan_block<<<nb1, 256, 0, stream>>>(counts, offsets, blocksums, nNodes);
    scan_sums<<<1, 512, 0, stream>>>(blocksums, nb1);
    add_offsets<<<nb1, 256, 0, stream>>>(offsets, cursor, blocksums, nNodes);
    fill_edges<<<nbe, 256, 0, stream>>>(src, dst, cursor, esrc, nEdges);

    // --- h = relu(X @ Wm^T + bm) [bf16] ; g = h @ Wo^T [bf16] ---
    gemm_mfma<1, 1><<<ngb, 256, 0, stream>>>(node_feats, wm_bf, b_msg, hbf, nNodes);
    gemm_mfma<0, 0><<<ngb, 256, 0, stream>>>(hbf, wo_bf, nullptr, gbf, nNodes);

    // --- out[d] = b_out + sum g[src[e]] ---
    gather_sum<<<(nNodes + 7) / 8, 256, 0, stream>>>(
        (const unsigned short*)gbf, offsets, cursor, esrc, b_out, out, nNodes);
}

// Round 5
// 172.880 us; speedup vs baseline: 14.5303x; 1.1619x over previous
//
#include <hip/hip_runtime.h>
#include <hip/hip_bf16.h>

#define NFEAT 128

typedef short bf16x8 __attribute__((ext_vector_type(8)));   // 8 bf16 as i16
typedef float f32x4  __attribute__((ext_vector_type(4)));
typedef unsigned short u16x8 __attribute__((ext_vector_type(8)));

static __device__ __forceinline__ short f2bf(float f) {
    __hip_bfloat16 h = __float2bfloat16(f);   // round-to-nearest
    return __builtin_bit_cast(short, h);
}
static __device__ __forceinline__ float bf2f(unsigned short u) {
    unsigned int x = ((unsigned int)u) << 16;
    return __builtin_bit_cast(float, x);
}

// ---------------------------------------------------------------------------
// Fused: g = (relu(X @ Wm^T + bm)) @ Wo^T, bf16 out, no intermediate in HBM.
// Block = 256 thr = 4 waves; wave w owns 16 rows x 128 cols.
// h-tile is transposed D-layout -> A-layout via a swizzled 4KB/wave LDS tile:
//   element (row,col) lives at short idx row*128 + ((col>>3) ^ (row&15))*8 + (col&7)
// Reads of 8 consecutive k at granule boundary recover one ds_read_b128.
// ---------------------------------------------------------------------------
__global__ __launch_bounds__(256) void gemm_fused(
    const float* __restrict__ X, const short* __restrict__ Wm,
    const float* __restrict__ bm, const short* __restrict__ Wo,
    short* __restrict__ G, int n)
{
    __shared__ short hs[4 * 16 * NFEAT];   // 16 KB
    const int w  = threadIdx.x >> 6;
    const int l  = threadIdx.x & 63;
    const int lr = l & 15;     // A row / B col / D col (within subtile)
    const int lk = l >> 4;     // k-group 0..3
    const int row0 = blockIdx.x * 64 + w * 16;
    short* hw = hs + w * 16 * NFEAT;

    // ---- GEMM1: h = relu(X @ Wm^T + bm) ----
    f32x4 acc1[8];
#pragma unroll
    for (int c = 0; c < 8; ++c) acc1[c] = (f32x4){0.f, 0.f, 0.f, 0.f};

    const int arow = min(row0 + lr, n - 1);   // clamp OOB loads (stores guarded)
#pragma unroll
    for (int k0 = 0; k0 < NFEAT; k0 += 32) {
        const int ka = k0 + lk * 8;
        const float* xp = X + (size_t)arow * NFEAT + ka;
        const float4 x0 = *(const float4*)xp;
        const float4 x1 = *(const float4*)(xp + 4);
        bf16x8 a;
        a[0] = f2bf(x0.x); a[1] = f2bf(x0.y); a[2] = f2bf(x0.z); a[3] = f2bf(x0.w);
        a[4] = f2bf(x1.x); a[5] = f2bf(x1.y); a[6] = f2bf(x1.z); a[7] = f2bf(x1.w);
#pragma unroll
        for (int c = 0; c < 8; ++c) {
            const bf16x8 b = *(const bf16x8*)(Wm + (size_t)(c * 16 + lr) * NFEAT + ka);
            acc1[c] = __builtin_amdgcn_mfma_f32_16x16x32_bf16(a, b, acc1[c], 0, 0, 0);
        }
    }

    // ---- bias+relu, store h-tile to swizzled LDS ----
#pragma unroll
    for (int c = 0; c < 8; ++c) {
        const int col = c * 16 + lr;
        const float bv = bm[col];
#pragma unroll
        for (int r = 0; r < 4; ++r) {
            const int row = lk * 4 + r;           // row within wave tile
            const float v = fmaxf(acc1[c][r] + bv, 0.f);
            const int g  = col >> 3;              // 16B granule
            const int gs = g ^ (row & 15);        // swizzle
            hw[row * NFEAT + gs * 8 + (col & 7)] = f2bf(v);
        }
    }
    __syncthreads();

    // ---- GEMM2: g = h @ Wo^T ----
    f32x4 acc2[8];
#pragma unroll
    for (int c = 0; c < 8; ++c) acc2[c] = (f32x4){0.f, 0.f, 0.f, 0.f};

#pragma unroll
    for (int k0 = 0; k0 < NFEAT; k0 += 32) {
        const int ka = k0 + lk * 8;
        const int gs = (ka >> 3) ^ (lr & 15);
        const bf16x8 a = *(const bf16x8*)(hw + lr * NFEAT + gs * 8);
#pragma unroll
        for (int c = 0; c < 8; ++c) {
            const bf16x8 b = *(const bf16x8*)(Wo + (size_t)(c * 16 + lr) * NFEAT + ka);
            acc2[c] = __builtin_amdgcn_mfma_f32_16x16x32_bf16(a, b, acc2[c], 0, 0, 0);
        }
    }

#pragma unroll
    for (int c = 0; c < 8; ++c) {
        const int col = c * 16 + lr;
#pragma unroll
        for (int r = 0; r < 4; ++r) {
            const int orow = row0 + lk * 4 + r;
            if (orow < n) G[(size_t)orow * NFEAT + col] = f2bf(acc2[c][r]);
        }
    }
}

// ---------------------------------------------------------------------------
// CSR build: convert weights (first 64 blocks) + degree count, one kernel.
// ---------------------------------------------------------------------------
__global__ __launch_bounds__(256) void convert_and_count(
    const float* __restrict__ wa, const float* __restrict__ wb,
    short* __restrict__ oa, short* __restrict__ ob,
    const int* __restrict__ dst, int* __restrict__ counts, int nE)
{
    const int i = blockIdx.x * 256 + threadIdx.x;
    if (i < NFEAT * NFEAT) { oa[i] = f2bf(wa[i]); ob[i] = f2bf(wb[i]); }
    if (i < nE) atomicAdd(&counts[dst[i]], 1);
}

__global__ __launch_bounds__(256) void scan_block(
    const int* __restrict__ counts, int* __restrict__ offsets,
    int* __restrict__ blocksums, int n)
{
    __shared__ int s[256];
    const int t = threadIdx.x;
    const int i = blockIdx.x * 256 + t;
    const int v = (i < n) ? counts[i] : 0;
    s[t] = v;
    __syncthreads();
    for (int off = 1; off < 256; off <<= 1) {
        const int add = (t >= off) ? s[t - off] : 0;
        __syncthreads();
        s[t] += add;
        __syncthreads();
    }
    if (i < n) offsets[i] = s[t] - v;
    if (t == 255) blocksums[blockIdx.x] = s[255];
}

// Each block redundantly reduces blocksums[0..blockIdx) then offsets += base.
__global__ __launch_bounds__(256) void add_offsets(
    int* __restrict__ offsets, int* __restrict__ cursor,
    const int* __restrict__ blocksums, int n)
{
    __shared__ int red[256];
    int partial = 0;
    for (int j = threadIdx.x; j < blockIdx.x; j += 256) partial += blocksums[j];
    red[threadIdx.x] = partial;
    __syncthreads();
    for (int s = 128; s > 0; s >>= 1) {
        if (threadIdx.x < s) red[threadIdx.x] += red[threadIdx.x + s];
        __syncthreads();
    }
    const int base = red[0];
    const int i = blockIdx.x * 256 + threadIdx.x;
    if (i < n) {
        const int o = offsets[i] + base;
        offsets[i] = o;
        cursor[i] = o;
    }
}

__global__ __launch_bounds__(256) void fill_edges(
    const int* __restrict__ src, const int* __restrict__ dst,
    int* __restrict__ cursor, int* __restrict__ esrc, int nE)
{
    const int i = blockIdx.x * 256 + threadIdx.x;
    if (i < nE) {
        const int p = atomicAdd(&cursor[dst[i]], 1);
        esrc[p] = src[i];
    }
}

// ---------------------------------------------------------------------------
// out[d] = b_out + sum_{e: dst=d} g[src[e]]   (g bf16, out f32).
// 16 lanes x ushort8 (16 B) per node; 16 nodes per 256-thread block.
// NT loads for esrc (streaming), NT stores for out (don't pollute L2/L3,
// keep g resident).
// ---------------------------------------------------------------------------
__global__ __launch_bounds__(256) void gather_sum(
    const unsigned short* __restrict__ g, const int* __restrict__ offsets,
    const int* __restrict__ cursor, const int* __restrict__ esrc,
    const float* __restrict__ bias, float* __restrict__ out, int nNodes)
{
    const int node = blockIdx.x * 16 + (threadIdx.x >> 4);
    const int lf = threadIdx.x & 15;            // feature group: 8 feats
    if (node >= nNodes) return;

    float acc[8];
    {
        const float4 b0 = *(const float4*)(bias + lf * 8);
        const float4 b1 = *(const float4*)(bias + lf * 8 + 4);
        acc[0] = b0.x; acc[1] = b0.y; acc[2] = b0.z; acc[3] = b0.w;
        acc[4] = b1.x; acc[5] = b1.y; acc[6] = b1.z; acc[7] = b1.w;
    }

    const int beg = offsets[node];
    const int end = cursor[node];
    int i = beg;
    for (; i + 2 <= end; i += 2) {
        const int s0 = __builtin_nontemporal_load(esrc + i);
        const int s1 = __builtin_nontemporal_load(esrc + i + 1);
        const u16x8 v0 = *(const u16x8*)(g + (size_t)s0 * NFEAT + lf * 8);
        const u16x8 v1 = *(const u16x8*)(g + (size_t)s1 * NFEAT + lf * 8);
#pragma unroll
        for (int j = 0; j < 8; ++j) acc[j] += bf2f(v0[j]) + bf2f(v1[j]);
    }
    if (i < end) {
        const int s0 = __builtin_nontemporal_load(esrc + i);
        const u16x8 v0 = *(const u16x8*)(g + (size_t)s0 * NFEAT + lf * 8);
#pragma unroll
        for (int j = 0; j < 8; ++j) acc[j] += bf2f(v0[j]);
    }

    float* op = out + (size_t)node * NFEAT + lf * 8;
    const f32x4 o0 = (f32x4){acc[0], acc[1], acc[2], acc[3]};
    const f32x4 o1 = (f32x4){acc[4], acc[5], acc[6], acc[7]};
    __builtin_nontemporal_store(o0, (f32x4*)op);
    __builtin_nontemporal_store(o1, (f32x4*)(op + 4));
}

extern "C" void kernel_launch(void* const* d_in, const int* in_sizes, int n_in,
                              void* d_out, int out_size, void* d_ws, size_t ws_size,
                              hipStream_t stream) {
    const float* node_feats = (const float*)d_in[0];
    const int*   src        = (const int*)d_in[1];
    const int*   dst        = (const int*)d_in[2];
    const float* W_msg      = (const float*)d_in[3];
    const float* b_msg      = (const float*)d_in[4];
    const float* W_out      = (const float*)d_in[5];
    const float* b_out      = (const float*)d_in[6];

    const int nNodes = in_sizes[0] / NFEAT;
    const int nEdges = in_sizes[1];

    float* out = (float*)d_out;

    // ws layout: gbf | wm_bf | wo_bf | counts | offsets | cursor | blocksums | esrc
    short* gbf      = (short*)d_ws;                                  // nNodes*128 bf16
    short* wm_bf    = gbf + (size_t)nNodes * NFEAT;                  // 16384 bf16
    short* wo_bf    = wm_bf + NFEAT * NFEAT;                         // 16384 bf16
    int*   counts   = (int*)(wo_bf + NFEAT * NFEAT);                 // nNodes
    int*   offsets  = counts + nNodes;                               // nNodes
    int*   cursor   = offsets + nNodes;                              // nNodes
    int*   blocksums= cursor + nNodes;                               // 512
    int*   esrc     = blocksums + 512;                               // nEdges

    const int nb1 = (nNodes + 255) / 256;   // 391
    const int nbe = (nEdges + 255) / 256;   // 2500
    const int ngb = (nNodes + 63) / 64;     // 1563

    // --- CSR build (+ weight conversion piggybacked) ---
    hipMemsetAsync(counts, 0, (size_t)nNodes * sizeof(int), stream);
    convert_and_count<<<nbe, 256, 0, stream>>>(W_msg, W_out, wm_bf, wo_bf, dst, counts, nEdges);
    scan_block<<<nb1, 256, 0, stream>>>(counts, offsets, blocksums, nNodes);
    add_offsets<<<nb1, 256, 0, stream>>>(offsets, cursor, blocksums, nNodes);
    fill_edges<<<nbe, 256, 0, stream>>>(src, dst, cursor, esrc, nEdges);

    // --- g = relu(X @ Wm^T + bm) @ Wo^T  [bf16, fused] ---
    gemm_fused<<<ngb, 256, 0, stream>>>(node_feats, wm_bf, b_msg, wo_bf, gbf, nNodes);

    // --- out[d] = b_out + sum g[src[e]] ---
    gather_sum<<<(nNodes + 15) / 16, 256, 0, stream>>>(
        (const unsigned short*)gbf, offsets, cursor, esrc, b_out, out, nNodes);
}

// Round 6
// 154.760 us; speedup vs baseline: 16.2315x; 1.1171x over previous
//
#include <hip/hip_runtime.h>
#include <hip/hip_bf16.h>

#define NFEAT 128

typedef short bf16x8 __attribute__((ext_vector_type(8)));   // 8 bf16 as i16
typedef float f32x4  __attribute__((ext_vector_type(4)));
typedef unsigned short u16x8 __attribute__((ext_vector_type(8)));

static __device__ __forceinline__ short f2bf(float f) {
    __hip_bfloat16 h = __float2bfloat16(f);   // round-to-nearest
    return __builtin_bit_cast(short, h);
}
static __device__ __forceinline__ float bf2f(unsigned short u) {
    unsigned int x = ((unsigned int)u) << 16;
    return __builtin_bit_cast(float, x);
}

// ---------------------------------------------------------------------------
// Fused: g = (relu(X @ Wm^T + bm)) @ Wo^T, bf16 out, no intermediate in HBM.
// Block = 256 thr = 4 waves; block tile 64 rows x 128 cols.
// NEW partition: wave w = ALL 64 rows x 32 cols [32w, 32w+32).
//   -> B operand (2 col-subtiles x 4 k-steps = 8 bf16x8 = 32 VGPR) is loaded
//      ONCE into registers; the row loop is pure {A-load, cvt, 8 MFMA}.
// h-tile transposed D-layout -> A-layout via swizzled LDS (16 KB):
//   element (row,col) at short idx row*128 + ((col>>3) ^ (row&15))*8 + (col&7)
// (same swizzle as round-5 kernel; measured SQ_LDS_BANK_CONFLICT = 0).
// ---------------------------------------------------------------------------
__global__ __launch_bounds__(256) void gemm_fused(
    const float* __restrict__ X, const short* __restrict__ Wm,
    const float* __restrict__ bm, const short* __restrict__ Wo,
    short* __restrict__ G, int n)
{
    __shared__ short hs[64 * NFEAT];   // 16 KB
    const int w  = threadIdx.x >> 6;
    const int l  = threadIdx.x & 63;
    const int lr = l & 15;     // A row / B col / D col (within subtile)
    const int lk = l >> 4;     // k-group 0..3
    const int row0 = blockIdx.x * 64;
    const int colw = w * 32;

    // ---- B1 (Wm) into registers: 8 x 16B loads ----
    bf16x8 b1[2][4];
#pragma unroll
    for (int c2 = 0; c2 < 2; ++c2)
#pragma unroll
        for (int k0 = 0; k0 < 4; ++k0)
            b1[c2][k0] = *(const bf16x8*)(Wm + (size_t)(colw + c2 * 16 + lr) * NFEAT
                                             + k0 * 32 + lk * 8);

    const float bv[2] = { bm[colw + lr], bm[colw + 16 + lr] };

    // ---- GEMM1: h = relu(X @ Wm^T + bm), row-tile loop ----
#pragma unroll
    for (int rt = 0; rt < 4; ++rt) {
        const int arow = min(row0 + rt * 16 + lr, n - 1);  // clamp OOB loads
        const float* xp = X + (size_t)arow * NFEAT + lk * 8;
        bf16x8 a[4];
#pragma unroll
        for (int k0 = 0; k0 < 4; ++k0) {
            const float4 x0 = *(const float4*)(xp + k0 * 32);
            const float4 x1 = *(const float4*)(xp + k0 * 32 + 4);
            a[k0][0] = f2bf(x0.x); a[k0][1] = f2bf(x0.y);
            a[k0][2] = f2bf(x0.z); a[k0][3] = f2bf(x0.w);
            a[k0][4] = f2bf(x1.x); a[k0][5] = f2bf(x1.y);
            a[k0][6] = f2bf(x1.z); a[k0][7] = f2bf(x1.w);
        }
        f32x4 acc1[2];
        acc1[0] = (f32x4){0.f, 0.f, 0.f, 0.f};
        acc1[1] = (f32x4){0.f, 0.f, 0.f, 0.f};
#pragma unroll
        for (int k0 = 0; k0 < 4; ++k0) {
            acc1[0] = __builtin_amdgcn_mfma_f32_16x16x32_bf16(a[k0], b1[0][k0], acc1[0], 0, 0, 0);
            acc1[1] = __builtin_amdgcn_mfma_f32_16x16x32_bf16(a[k0], b1[1][k0], acc1[1], 0, 0, 0);
        }
        // bias+relu, store to swizzled LDS
#pragma unroll
        for (int c2 = 0; c2 < 2; ++c2) {
            const int col = colw + c2 * 16 + lr;
            const int gi  = col >> 3;
#pragma unroll
            for (int r = 0; r < 4; ++r) {
                const int row = rt * 16 + lk * 4 + r;
                const float v = fmaxf(acc1[c2][r] + bv[c2], 0.f);
                hs[row * NFEAT + (gi ^ (row & 15)) * 8 + (col & 7)] = f2bf(v);
            }
        }
    }

    // ---- B2 (Wo) into registers (issued before barrier; independent) ----
    bf16x8 b2[2][4];
#pragma unroll
    for (int c2 = 0; c2 < 2; ++c2)
#pragma unroll
        for (int k0 = 0; k0 < 4; ++k0)
            b2[c2][k0] = *(const bf16x8*)(Wo + (size_t)(colw + c2 * 16 + lr) * NFEAT
                                             + k0 * 32 + lk * 8);

    __syncthreads();

    // ---- GEMM2: g = h @ Wo^T ----
#pragma unroll
    for (int rt = 0; rt < 4; ++rt) {
        bf16x8 a[4];
#pragma unroll
        for (int k0 = 0; k0 < 4; ++k0) {
            const int row = rt * 16 + lr;
            const int gs  = (k0 * 4 + lk) ^ (row & 15);
            a[k0] = *(const bf16x8*)(hs + row * NFEAT + gs * 8);
        }
        f32x4 acc2[2];
        acc2[0] = (f32x4){0.f, 0.f, 0.f, 0.f};
        acc2[1] = (f32x4){0.f, 0.f, 0.f, 0.f};
#pragma unroll
        for (int k0 = 0; k0 < 4; ++k0) {
            acc2[0] = __builtin_amdgcn_mfma_f32_16x16x32_bf16(a[k0], b2[0][k0], acc2[0], 0, 0, 0);
            acc2[1] = __builtin_amdgcn_mfma_f32_16x16x32_bf16(a[k0], b2[1][k0], acc2[1], 0, 0, 0);
        }
#pragma unroll
        for (int c2 = 0; c2 < 2; ++c2) {
            const int col = colw + c2 * 16 + lr;
#pragma unroll
            for (int r = 0; r < 4; ++r) {
                const int orow = row0 + rt * 16 + lk * 4 + r;
                if (orow < n) G[(size_t)orow * NFEAT + col] = f2bf(acc2[c2][r]);
            }
        }
    }
}

// ---------------------------------------------------------------------------
// CSR build: convert weights (first 64 blocks) + degree count, one kernel.
// ---------------------------------------------------------------------------
__global__ __launch_bounds__(256) void convert_and_count(
    const float* __restrict__ wa, const float* __restrict__ wb,
    short* __restrict__ oa, short* __restrict__ ob,
    const int* __restrict__ dst, int* __restrict__ counts, int nE)
{
    const int i = blockIdx.x * 256 + threadIdx.x;
    if (i < NFEAT * NFEAT) { oa[i] = f2bf(wa[i]); ob[i] = f2bf(wb[i]); }
    if (i < nE) atomicAdd(&counts[dst[i]], 1);
}

__global__ __launch_bounds__(256) void scan_block(
    const int* __restrict__ counts, int* __restrict__ offsets,
    int* __restrict__ blocksums, int n)
{
    __shared__ int s[256];
    const int t = threadIdx.x;
    const int i = blockIdx.x * 256 + t;
    const int v = (i < n) ? counts[i] : 0;
    s[t] = v;
    __syncthreads();
    for (int off = 1; off < 256; off <<= 1) {
        const int add = (t >= off) ? s[t - off] : 0;
        __syncthreads();
        s[t] += add;
        __syncthreads();
    }
    if (i < n) offsets[i] = s[t] - v;
    if (t == 255) blocksums[blockIdx.x] = s[255];
}

// Each block redundantly reduces blocksums[0..blockIdx) then offsets += base.
__global__ __launch_bounds__(256) void add_offsets(
    int* __restrict__ offsets, int* __restrict__ cursor,
    const int* __restrict__ blocksums, int n)
{
    __shared__ int red[256];
    int partial = 0;
    for (int j = threadIdx.x; j < blockIdx.x; j += 256) partial += blocksums[j];
    red[threadIdx.x] = partial;
    __syncthreads();
    for (int s = 128; s > 0; s >>= 1) {
        if (threadIdx.x < s) red[threadIdx.x] += red[threadIdx.x + s];
        __syncthreads();
    }
    const int base = red[0];
    const int i = blockIdx.x * 256 + threadIdx.x;
    if (i < n) {
        const int o = offsets[i] + base;
        offsets[i] = o;
        cursor[i] = o;
    }
}

__global__ __launch_bounds__(256) void fill_edges(
    const int* __restrict__ src, const int* __restrict__ dst,
    int* __restrict__ cursor, int* __restrict__ esrc, int nE)
{
    const int i = blockIdx.x * 256 + threadIdx.x;
    if (i < nE) {
        const int p = atomicAdd(&cursor[dst[i]], 1);
        esrc[p] = src[i];
    }
}

// ---------------------------------------------------------------------------
// out[d] = b_out + sum_{e: dst=d} g[src[e]]   (g bf16, out f32).
// 16 lanes x ushort8 (16 B) per node; 16 nodes per 256-thread block.
// ---------------------------------------------------------------------------
__global__ __launch_bounds__(256) void gather_sum(
    const unsigned short* __restrict__ g, const int* __restrict__ offsets,
    const int* __restrict__ cursor, const int* __restrict__ esrc,
    const float* __restrict__ bias, float* __restrict__ out, int nNodes)
{
    const int node = blockIdx.x * 16 + (threadIdx.x >> 4);
    const int lf = threadIdx.x & 15;            // feature group: 8 feats
    if (node >= nNodes) return;

    float acc[8];
    {
        const float4 b0 = *(const float4*)(bias + lf * 8);
        const float4 b1 = *(const float4*)(bias + lf * 8 + 4);
        acc[0] = b0.x; acc[1] = b0.y; acc[2] = b0.z; acc[3] = b0.w;
        acc[4] = b1.x; acc[5] = b1.y; acc[6] = b1.z; acc[7] = b1.w;
    }

    const int beg = offsets[node];
    const int end = cursor[node];
    int i = beg;
    for (; i + 2 <= end; i += 2) {
        const int s0 = __builtin_nontemporal_load(esrc + i);
        const int s1 = __builtin_nontemporal_load(esrc + i + 1);
        const u16x8 v0 = *(const u16x8*)(g + (size_t)s0 * NFEAT + lf * 8);
        const u16x8 v1 = *(const u16x8*)(g + (size_t)s1 * NFEAT + lf * 8);
#pragma unroll
        for (int j = 0; j < 8; ++j) acc[j] += bf2f(v0[j]) + bf2f(v1[j]);
    }
    if (i < end) {
        const int s0 = __builtin_nontemporal_load(esrc + i);
        const u16x8 v0 = *(const u16x8*)(g + (size_t)s0 * NFEAT + lf * 8);
#pragma unroll
        for (int j = 0; j < 8; ++j) acc[j] += bf2f(v0[j]);
    }

    float* op = out + (size_t)node * NFEAT + lf * 8;
    const f32x4 o0 = (f32x4){acc[0], acc[1], acc[2], acc[3]};
    const f32x4 o1 = (f32x4){acc[4], acc[5], acc[6], acc[7]};
    __builtin_nontemporal_store(o0, (f32x4*)op);
    __builtin_nontemporal_store(o1, (f32x4*)(op + 4));
}

extern "C" void kernel_launch(void* const* d_in, const int* in_sizes, int n_in,
                              void* d_out, int out_size, void* d_ws, size_t ws_size,
                              hipStream_t stream) {
    const float* node_feats = (const float*)d_in[0];
    const int*   src        = (const int*)d_in[1];
    const int*   dst        = (const int*)d_in[2];
    const float* W_msg      = (const float*)d_in[3];
    const float* b_msg      = (const float*)d_in[4];
    const float* W_out      = (const float*)d_in[5];
    const float* b_out      = (const float*)d_in[6];

    const int nNodes = in_sizes[0] / NFEAT;
    const int nEdges = in_sizes[1];

    float* out = (float*)d_out;

    // ws layout: gbf | wm_bf | wo_bf | counts | offsets | cursor | blocksums | esrc
    short* gbf      = (short*)d_ws;                                  // nNodes*128 bf16
    short* wm_bf    = gbf + (size_t)nNodes * NFEAT;                  // 16384 bf16
    short* wo_bf    = wm_bf + NFEAT * NFEAT;                         // 16384 bf16
    int*   counts   = (int*)(wo_bf + NFEAT * NFEAT);                 // nNodes
    int*   offsets  = counts + nNodes;                               // nNodes
    int*   cursor   = offsets + nNodes;                              // nNodes
    int*   blocksums= cursor + nNodes;                               // 512
    int*   esrc     = blocksums + 512;                               // nEdges

    const int nb1 = (nNodes + 255) / 256;   // 391
    const int nbe = (nEdges + 255) / 256;   // 2500
    const int ngb = (nNodes + 63) / 64;     // 1563

    // --- CSR build (+ weight conversion piggybacked) ---
    hipMemsetAsync(counts, 0, (size_t)nNodes * sizeof(int), stream);
    convert_and_count<<<nbe, 256, 0, stream>>>(W_msg, W_out, wm_bf, wo_bf, dst, counts, nEdges);
    scan_block<<<nb1, 256, 0, stream>>>(counts, offsets, blocksums, nNodes);
    add_offsets<<<nb1, 256, 0, stream>>>(offsets, cursor, blocksums, nNodes);
    fill_edges<<<nbe, 256, 0, stream>>>(src, dst, cursor, esrc, nEdges);

    // --- g = relu(X @ Wm^T + bm) @ Wo^T  [bf16, fused] ---
    gemm_fused<<<ngb, 256, 0, stream>>>(node_feats, wm_bf, b_msg, wo_bf, gbf, nNodes);

    // --- out[d] = b_out + sum g[src[e]] ---
    gather_sum<<<(nNodes + 15) / 16, 256, 0, stream>>>(
        (const unsigned short*)gbf, offsets, cursor, esrc, b_out, out, nNodes);
}

// Round 7
// 134.291 us; speedup vs baseline: 18.7056x; 1.1524x over previous
//
#include <hip/hip_runtime.h>
#include <hip/hip_bf16.h>

#define NFEAT 128

typedef short bf16x8 __attribute__((ext_vector_type(8)));   // 8 bf16 as i16
typedef float f32x4  __attribute__((ext_vector_type(4)));
typedef unsigned short u16x8 __attribute__((ext_vector_type(8)));

static __device__ __forceinline__ short f2bf(float f) {
    __hip_bfloat16 h = __float2bfloat16(f);   // round-to-nearest
    return __builtin_bit_cast(short, h);
}
static __device__ __forceinline__ float bf2f(unsigned short u) {
    unsigned int x = ((unsigned int)u) << 16;
    return __builtin_bit_cast(float, x);
}

// ---------------------------------------------------------------------------
// Fused: g = (relu(X @ Wm^T + bm)) @ Wo^T, bf16 out.
// Block = 256 thr = 4 waves, 128 rows = 2 panels x 64 rows.
// Wave w owns cols [32w, 32w+32) for all rows; B1/B2 reg-resident (64 VGPR).
// X panel staged COOPERATIVELY (once per block) into LDS as bf16 with
// granule-XOR swizzle: elem (row,col) at row*128 + ((col>>3)^(row&15))*8 + (col&7)
//   -> ds_write_b128 / ds_read_b128, all accesses <=2-way (free).
// Panel pipeline: loads of panel p+1 issue before GEMM1(p) (reg-held, T14);
// h-tile overwrites consumed X buffer. 2 barriers/panel.
// ---------------------------------------------------------------------------
__global__ __launch_bounds__(256) void gemm_fused(
    const float* __restrict__ X, const short* __restrict__ Wm,
    const float* __restrict__ bm, const short* __restrict__ Wo,
    short* __restrict__ G, int n)
{
    __shared__ short xb[2][64 * NFEAT];   // 2 x 16 KB
    const int t  = threadIdx.x;
    const int w  = t >> 6;
    const int l  = t & 63;
    const int lr = l & 15;     // A row / B col / D col (within subtile)
    const int lk = l >> 4;     // k-group 0..3
    const int row0 = blockIdx.x * 128;
    const int colw = w * 32;

    // ---- B operands into registers (per-wave 32-col slice of Wm and Wo) ----
    bf16x8 b1[2][4], b2[2][4];
#pragma unroll
    for (int c2 = 0; c2 < 2; ++c2)
#pragma unroll
        for (int k0 = 0; k0 < 4; ++k0) {
            const size_t off = (size_t)(colw + c2 * 16 + lr) * NFEAT + k0 * 32 + lk * 8;
            b1[c2][k0] = *(const bf16x8*)(Wm + off);
            b2[c2][k0] = *(const bf16x8*)(Wo + off);
        }
    const float bv0 = bm[colw + lr];
    const float bv1 = bm[colw + 16 + lr];

    // ---- stage panel 0: 8 float4 loads -> bf16 -> swizzled LDS ----
    float4 pf[8];
#pragma unroll
    for (int i = 0; i < 4; ++i) {
        const int row = min(row0 + i * 16 + (t >> 4), n - 1);
        const float* p = X + (size_t)row * NFEAT + (t & 15) * 8;
        pf[2 * i]     = *(const float4*)p;
        pf[2 * i + 1] = *(const float4*)(p + 4);
    }
#pragma unroll
    for (int i = 0; i < 4; ++i) {
        const int rl = i * 16 + (t >> 4);
        const int g  = (t & 15) ^ (rl & 15);
        bf16x8 v;
        v[0] = f2bf(pf[2*i].x);   v[1] = f2bf(pf[2*i].y);
        v[2] = f2bf(pf[2*i].z);   v[3] = f2bf(pf[2*i].w);
        v[4] = f2bf(pf[2*i+1].x); v[5] = f2bf(pf[2*i+1].y);
        v[6] = f2bf(pf[2*i+1].z); v[7] = f2bf(pf[2*i+1].w);
        *(bf16x8*)(&xb[0][rl * NFEAT + g * 8]) = v;
    }
    __syncthreads();

#pragma unroll
    for (int p = 0; p < 2; ++p) {
        short* cur = &xb[p][0];

        // ---- prefetch panel 1 global loads (issued before GEMM1 compute) ----
        if (p == 0) {
#pragma unroll
            for (int i = 0; i < 4; ++i) {
                const int row = min(row0 + 64 + i * 16 + (t >> 4), n - 1);
                const float* q = X + (size_t)row * NFEAT + (t & 15) * 8;
                pf[2 * i]     = *(const float4*)q;
                pf[2 * i + 1] = *(const float4*)(q + 4);
            }
        }

        // ---- GEMM1: h = relu(X @ Wm^T + bm) for this panel ----
        f32x4 acc[4][2];
#pragma unroll
        for (int rt = 0; rt < 4; ++rt) {
            acc[rt][0] = (f32x4){0.f, 0.f, 0.f, 0.f};
            acc[rt][1] = (f32x4){0.f, 0.f, 0.f, 0.f};
        }
#pragma unroll
        for (int rt = 0; rt < 4; ++rt) {
            bf16x8 a[4];
#pragma unroll
            for (int k0 = 0; k0 < 4; ++k0)
                a[k0] = *(const bf16x8*)(cur + (rt * 16 + lr) * NFEAT + ((k0 * 4 + lk) ^ lr) * 8);
#pragma unroll
            for (int k0 = 0; k0 < 4; ++k0) {
                acc[rt][0] = __builtin_amdgcn_mfma_f32_16x16x32_bf16(a[k0], b1[0][k0], acc[rt][0], 0, 0, 0);
                acc[rt][1] = __builtin_amdgcn_mfma_f32_16x16x32_bf16(a[k0], b1[1][k0], acc[rt][1], 0, 0, 0);
            }
        }
        __syncthreads();   // all A-reads of cur done; stage-writes of next may land

        // ---- h-write (bias+relu) overwrites cur; staged write of panel 1 ----
#pragma unroll
        for (int rt = 0; rt < 4; ++rt)
#pragma unroll
            for (int c2 = 0; c2 < 2; ++c2) {
                const int col = colw + c2 * 16 + lr;
                const int gc  = col >> 3;
                const float bv = c2 ? bv1 : bv0;
#pragma unroll
                for (int r = 0; r < 4; ++r) {
                    const int row = rt * 16 + lk * 4 + r;
                    const float v = fmaxf(acc[rt][c2][r] + bv, 0.f);
                    cur[row * NFEAT + (gc ^ (row & 15)) * 8 + (col & 7)] = f2bf(v);
                }
            }
        if (p == 0) {
#pragma unroll
            for (int i = 0; i < 4; ++i) {
                const int rl = i * 16 + (t >> 4);
                const int g  = (t & 15) ^ (rl & 15);
                bf16x8 v;
                v[0] = f2bf(pf[2*i].x);   v[1] = f2bf(pf[2*i].y);
                v[2] = f2bf(pf[2*i].z);   v[3] = f2bf(pf[2*i].w);
                v[4] = f2bf(pf[2*i+1].x); v[5] = f2bf(pf[2*i+1].y);
                v[6] = f2bf(pf[2*i+1].z); v[7] = f2bf(pf[2*i+1].w);
                *(bf16x8*)(&xb[1][rl * NFEAT + g * 8]) = v;
            }
        }
        __syncthreads();   // h (and next X) visible

        // ---- GEMM2: g = h @ Wo^T, store bf16 ----
#pragma unroll
        for (int rt = 0; rt < 4; ++rt) {
            bf16x8 a[4];
#pragma unroll
            for (int k0 = 0; k0 < 4; ++k0)
                a[k0] = *(const bf16x8*)(cur + (rt * 16 + lr) * NFEAT + ((k0 * 4 + lk) ^ lr) * 8);
            f32x4 c0 = (f32x4){0.f, 0.f, 0.f, 0.f};
            f32x4 c1 = (f32x4){0.f, 0.f, 0.f, 0.f};
#pragma unroll
            for (int k0 = 0; k0 < 4; ++k0) {
                c0 = __builtin_amdgcn_mfma_f32_16x16x32_bf16(a[k0], b2[0][k0], c0, 0, 0, 0);
                c1 = __builtin_amdgcn_mfma_f32_16x16x32_bf16(a[k0], b2[1][k0], c1, 0, 0, 0);
            }
#pragma unroll
            for (int c2 = 0; c2 < 2; ++c2) {
                const int col = colw + c2 * 16 + lr;
#pragma unroll
                for (int r = 0; r < 4; ++r) {
                    const int orow = row0 + p * 64 + rt * 16 + lk * 4 + r;
                    const float v = c2 ? c1[r] : c0[r];
                    if (orow < n) G[(size_t)orow * NFEAT + col] = f2bf(v);
                }
            }
        }
        // no end-of-panel barrier needed: next panel reads the OTHER buffer,
        // and its h-write is fenced by its own post-GEMM1 barrier.
    }
}

// ---------------------------------------------------------------------------
// CSR build: convert weights (first 64 blocks) + degree count, one kernel.
// ---------------------------------------------------------------------------
__global__ __launch_bounds__(256) void convert_and_count(
    const float* __restrict__ wa, const float* __restrict__ wb,
    short* __restrict__ oa, short* __restrict__ ob,
    const int* __restrict__ dst, int* __restrict__ counts, int nE)
{
    const int i = blockIdx.x * 256 + threadIdx.x;
    if (i < NFEAT * NFEAT) { oa[i] = f2bf(wa[i]); ob[i] = f2bf(wb[i]); }
    if (i < nE) atomicAdd(&counts[dst[i]], 1);
}

__global__ __launch_bounds__(256) void scan_block(
    const int* __restrict__ counts, int* __restrict__ offsets,
    int* __restrict__ blocksums, int n)
{
    __shared__ int s[256];
    const int t = threadIdx.x;
    const int i = blockIdx.x * 256 + t;
    const int v = (i < n) ? counts[i] : 0;
    s[t] = v;
    __syncthreads();
    for (int off = 1; off < 256; off <<= 1) {
        const int add = (t >= off) ? s[t - off] : 0;
        __syncthreads();
        s[t] += add;
        __syncthreads();
    }
    if (i < n) offsets[i] = s[t] - v;
    if (t == 255) blocksums[blockIdx.x] = s[255];
}

// Each block redundantly reduces blocksums[0..blockIdx) then offsets += base.
__global__ __launch_bounds__(256) void add_offsets(
    int* __restrict__ offsets, int* __restrict__ cursor,
    const int* __restrict__ blocksums, int n)
{
    __shared__ int red[256];
    int partial = 0;
    for (int j = threadIdx.x; j < blockIdx.x; j += 256) partial += blocksums[j];
    red[threadIdx.x] = partial;
    __syncthreads();
    for (int s = 128; s > 0; s >>= 1) {
        if (threadIdx.x < s) red[threadIdx.x] += red[threadIdx.x + s];
        __syncthreads();
    }
    const int base = red[0];
    const int i = blockIdx.x * 256 + threadIdx.x;
    if (i < n) {
        const int o = offsets[i] + base;
        offsets[i] = o;
        cursor[i] = o;
    }
}

__global__ __launch_bounds__(256) void fill_edges(
    const int* __restrict__ src, const int* __restrict__ dst,
    int* __restrict__ cursor, int* __restrict__ esrc, int nE)
{
    const int i = blockIdx.x * 256 + threadIdx.x;
    if (i < nE) {
        const int p = atomicAdd(&cursor[dst[i]], 1);
        esrc[p] = src[i];
    }
}

// ---------------------------------------------------------------------------
// out[d] = b_out + sum_{e: dst=d} g[src[e]]   (g bf16, out f32).
// 16 lanes x ushort8 (16 B) per node; 16 nodes per 256-thread block.
// ---------------------------------------------------------------------------
__global__ __launch_bounds__(256) void gather_sum(
    const unsigned short* __restrict__ g, const int* __restrict__ offsets,
    const int* __restrict__ cursor, const int* __restrict__ esrc,
    const float* __restrict__ bias, float* __restrict__ out, int nNodes)
{
    const int node = blockIdx.x * 16 + (threadIdx.x >> 4);
    const int lf = threadIdx.x & 15;            // feature group: 8 feats
    if (node >= nNodes) return;

    float acc[8];
    {
        const float4 b0 = *(const float4*)(bias + lf * 8);
        const float4 b1 = *(const float4*)(bias + lf * 8 + 4);
        acc[0] = b0.x; acc[1] = b0.y; acc[2] = b0.z; acc[3] = b0.w;
        acc[4] = b1.x; acc[5] = b1.y; acc[6] = b1.z; acc[7] = b1.w;
    }

    const int beg = offsets[node];
    const int end = cursor[node];
    int i = beg;
    for (; i + 2 <= end; i += 2) {
        const int s0 = __builtin_nontemporal_load(esrc + i);
        const int s1 = __builtin_nontemporal_load(esrc + i + 1);
        const u16x8 v0 = *(const u16x8*)(g + (size_t)s0 * NFEAT + lf * 8);
        const u16x8 v1 = *(const u16x8*)(g + (size_t)s1 * NFEAT + lf * 8);
#pragma unroll
        for (int j = 0; j < 8; ++j) acc[j] += bf2f(v0[j]) + bf2f(v1[j]);
    }
    if (i < end) {
        const int s0 = __builtin_nontemporal_load(esrc + i);
        const u16x8 v0 = *(const u16x8*)(g + (size_t)s0 * NFEAT + lf * 8);
#pragma unroll
        for (int j = 0; j < 8; ++j) acc[j] += bf2f(v0[j]);
    }

    float* op = out + (size_t)node * NFEAT + lf * 8;
    const f32x4 o0 = (f32x4){acc[0], acc[1], acc[2], acc[3]};
    const f32x4 o1 = (f32x4){acc[4], acc[5], acc[6], acc[7]};
    __builtin_nontemporal_store(o0, (f32x4*)op);
    __builtin_nontemporal_store(o1, (f32x4*)(op + 4));
}

extern "C" void kernel_launch(void* const* d_in, const int* in_sizes, int n_in,
                              void* d_out, int out_size, void* d_ws, size_t ws_size,
                              hipStream_t stream) {
    const float* node_feats = (const float*)d_in[0];
    const int*   src        = (const int*)d_in[1];
    const int*   dst        = (const int*)d_in[2];
    const float* W_msg      = (const float*)d_in[3];
    const float* b_msg      = (const float*)d_in[4];
    const float* W_out      = (const float*)d_in[5];
    const float* b_out      = (const float*)d_in[6];

    const int nNodes = in_sizes[0] / NFEAT;
    const int nEdges = in_sizes[1];

    float* out = (float*)d_out;

    // ws layout: gbf | wm_bf | wo_bf | counts | offsets | cursor | blocksums | esrc
    short* gbf      = (short*)d_ws;                                  // nNodes*128 bf16
    short* wm_bf    = gbf + (size_t)nNodes * NFEAT;                  // 16384 bf16
    short* wo_bf    = wm_bf + NFEAT * NFEAT;                         // 16384 bf16
    int*   counts   = (int*)(wo_bf + NFEAT * NFEAT);                 // nNodes
    int*   offsets  = counts + nNodes;                               // nNodes
    int*   cursor   = offsets + nNodes;                              // nNodes
    int*   blocksums= cursor + nNodes;                               // 512
    int*   esrc     = blocksums + 512;                               // nEdges

    const int nb1 = (nNodes + 255) / 256;   // 391
    const int nbe = (nEdges + 255) / 256;   // 2500
    const int ngb = (nNodes + 127) / 128;   // 782

    // --- CSR build (+ weight conversion piggybacked) ---
    hipMemsetAsync(counts, 0, (size_t)nNodes * sizeof(int), stream);
    convert_and_count<<<nbe, 256, 0, stream>>>(W_msg, W_out, wm_bf, wo_bf, dst, counts, nEdges);
    scan_block<<<nb1, 256, 0, stream>>>(counts, offsets, blocksums, nNodes);
    add_offsets<<<nb1, 256, 0, stream>>>(offsets, cursor, blocksums, nNodes);
    fill_edges<<<nbe, 256, 0, stream>>>(src, dst, cursor, esrc, nEdges);

    // --- g = relu(X @ Wm^T + bm) @ Wo^T  [bf16, fused, 2-panel pipelined] ---
    gemm_fused<<<ngb, 256, 0, stream>>>(node_feats, wm_bf, b_msg, wo_bf, gbf, nNodes);

    // --- out[d] = b_out + sum g[src[e]] ---
    gather_sum<<<(nNodes + 15) / 16, 256, 0, stream>>>(
        (const unsigned short*)gbf, offsets, cursor, esrc, b_out, out, nNodes);
}